// Round 12
// baseline (324.267 us; speedup 1.0000x reference)
//
#include <hip/hip_runtime.h>

// ---------- types & helpers ----------
typedef __attribute__((ext_vector_type(8))) __bf16 bf16x8;
typedef __attribute__((ext_vector_type(4))) float f32x4;
typedef __attribute__((ext_vector_type(8))) ushort ushort8;

#define GLP(p) ((const __attribute__((address_space(1))) void*)(p))
#define LDP(p) ((__attribute__((address_space(3))) void*)(p))

__device__ __forceinline__ ushort f2b(float f) {
  union { float f; uint u; } c; c.f = f;
  uint u = c.u;
  uint r = (u + 0x7fffu + ((u >> 16) & 1u)) >> 16;
  return (ushort)r;
}
__device__ __forceinline__ float b2f(ushort b) {
  union { uint u; float f; } c; c.u = ((uint)b) << 16;
  return c.f;
}

// bijective XCD swizzle, row-chunks (good for square attention grids; r10).
__device__ __forceinline__ void xcd_tiles(int& tileN, int& tileM) {
  const int gx = gridDim.x;
  const int nwg = gx * gridDim.y;
  int id = blockIdx.x + gx * blockIdx.y;
  id = (id & 7) * (nwg >> 3) + (id >> 3);
  tileN = (id % gx) * 128;
  tileM = (id / gx) * 128;
}

__device__ __forceinline__ float block_reduce_sum(float v, float* sm) {
#pragma unroll
  for (int off = 1; off < 64; off <<= 1) v += __shfl_xor(v, off);
  const int wave = threadIdx.x >> 6, lane = threadIdx.x & 63;
  __syncthreads();
  if (lane == 0) sm[wave] = v;
  __syncthreads();
  return sm[0] + sm[1] + sm[2] + sm[3];
}

// ---------- fused weight transpose + bf16 convert for all 6 weights ----------
__global__ __launch_bounds__(256) void wtrans6_kernel(
    const float* __restrict__ W0, const float* __restrict__ W1,
    const float* __restrict__ W2, const float* __restrict__ W3,
    const float* __restrict__ W4, const float* __restrict__ W5,
    ushort* __restrict__ T0, ushort* __restrict__ T1, ushort* __restrict__ T2,
    ushort* __restrict__ T3, ushort* __restrict__ T4, ushort* __restrict__ T5) {
  __shared__ float tile[32][33];
  const float* Ws[6] = {W0, W1, W2, W3, W4, W5};
  ushort* Ts[6] = {T0, T1, T2, T3, T4, T5};
  const float* W = Ws[blockIdx.z];
  ushort* Wt = Ts[blockIdx.z];
  const int K = 1024, N = 1024;
  const int n0 = blockIdx.x * 32, k0 = blockIdx.y * 32;
  const int tx = threadIdx.x, ty = threadIdx.y;  // block (32,8)
#pragma unroll
  for (int i = 0; i < 32; i += 8)
    tile[ty + i][tx] = W[(long)(k0 + ty + i) * N + n0 + tx];
  __syncthreads();
#pragma unroll
  for (int i = 0; i < 32; i += 8)
    Wt[(long)(n0 + ty + i) * K + k0 + tx] = f2b(tile[tx][ty + i]);
}

// ---------- LayerNorm (row of 1024) -> bf16 ----------
__global__ __launch_bounds__(256) void layernorm_kernel(
    const float* __restrict__ x, const float* __restrict__ g,
    const float* __restrict__ be, ushort* __restrict__ out) {
  __shared__ float sm[4];
  const long row = blockIdx.x;
  const float4 v = reinterpret_cast<const float4*>(x + row * 1024)[threadIdx.x];
  float s = v.x + v.y + v.z + v.w;
  s = block_reduce_sum(s, sm);
  const float mu = s * (1.0f / 1024.0f);
  const float dx = v.x - mu, dy = v.y - mu, dz = v.z - mu, dw = v.w - mu;
  float s2 = dx * dx + dy * dy + dz * dz + dw * dw;
  s2 = block_reduce_sum(s2, sm);
  const float rstd = rsqrtf(s2 * (1.0f / 1024.0f) + 1e-5f);
  const float4 gg = reinterpret_cast<const float4*>(g)[threadIdx.x];
  const float4 bb = reinterpret_cast<const float4*>(be)[threadIdx.x];
  ushort4 o;
  o.x = f2b(dx * rstd * gg.x + bb.x);
  o.y = f2b(dy * rstd * gg.y + bb.y);
  o.z = f2b(dz * rstd * gg.z + bb.z);
  o.w = f2b(dw * rstd * gg.w + bb.w);
  reinterpret_cast<ushort4*>(out + row * 1024)[threadIdx.x] = o;
}

// ---------- row-normalize: e(bf16) -> w(fp32, normalized) + invZ ----------
__global__ __launch_bounds__(256) void rownorm_kernel(
    const ushort* __restrict__ e, float* __restrict__ w, float* __restrict__ invZ) {
  __shared__ float sm[4];
  const long row = blockIdx.x;
  const ushort8 v = *reinterpret_cast<const ushort8*>(e + row * 2048 + threadIdx.x * 8);
  float f[8];
  float s = 0.0f;
#pragma unroll
  for (int i = 0; i < 8; ++i) {
    f[i] = b2f(v[i]);
    s += f[i];
  }
  s = block_reduce_sum(s, sm);
  const float inv = 1.0f / s;
  if (threadIdx.x == 0) invZ[row] = inv;
  float4 o0 = {f[0] * inv, f[1] * inv, f[2] * inv, f[3] * inv};
  float4 o1 = {f[4] * inv, f[5] * inv, f[6] * inv, f[7] * inv};
  float4* wp = reinterpret_cast<float4*>(w + row * 2048);
  wp[threadIdx.x * 2] = o0;
  wp[threadIdx.x * 2 + 1] = o1;
}

// ---------- 128x128 GEMM, 8 waves, 4-slot 2-step-unrolled prefetch ----------
#define EP_BF16 1
#define EP_F32 2
#define EP_BIAS 4
#define EP_RELU 8
#define EP_SCALE 16
#define EP_RESID 32
#define EP_TRANS 64
#define EP_EXP 128     // v = exp(v) after scale (QK^T -> e)
#define EP_ROWSC 256   // v *= rowsc[z*M + row]  (PV normalization)
#define EP_SWZ 512     // apply XCD tile swizzle

template <int FLAGS>
__global__ __launch_bounds__(512) void gemm_bt(
    const ushort* __restrict__ A, const ushort* __restrict__ Bt,
    float* __restrict__ Cf, ushort* __restrict__ Cb,
    const float* __restrict__ bias, const float* __restrict__ resid,
    const float* __restrict__ rowsc,
    int M, int N, int K, float scale, long sA, long sB, long sC) {
  A += (long)blockIdx.z * sA;
  Bt += (long)blockIdx.z * sB;
  const long coff = (long)blockIdx.z * sC;
  const long rbase = (long)blockIdx.z * M;
  int tileN, tileM;
  if (FLAGS & EP_SWZ) {
    xcd_tiles(tileN, tileM);
  } else {
    tileN = blockIdx.x * 128;
    tileM = blockIdx.y * 128;
  }
  const int tid = threadIdx.x, lane = tid & 63, wid = tid >> 6;  // 8 waves
  const int wm = wid >> 2, wn = wid & 3;
  __shared__ alignas(16) ushort As[4][128][32];
  __shared__ alignas(16) ushort Bs[4][128][32];
  f32x4 acc[4][2] = {};

  const int srow = wid * 16 + (lane >> 2);
  const int scol = (lane & 3) * 8;
  const ushort* aP = A + (long)(tileM + srow) * K + scol;
  const ushort* bP = Bt + (long)(tileN + srow) * K + scol;

#define STAGE(slot, kk)                                                                  \
  do {                                                                                   \
    __builtin_amdgcn_global_load_lds(GLP(aP + (kk)), LDP(&As[slot][wid * 16][0]), 16, 0, \
                                     0);                                                 \
    __builtin_amdgcn_global_load_lds(GLP(bP + (kk)), LDP(&Bs[slot][wid * 16][0]), 16, 0, \
                                     0);                                                 \
  } while (0)

  STAGE(0, 0);
  STAGE(1, 32);
  __syncthreads();
  int cur = 0;
  for (int kk = 0; kk < K; kk += 64) {
    const int nxt = cur ^ 2;
    if (kk + 64 < K) {
      STAGE(nxt, kk + 64);
      STAGE(nxt + 1, kk + 96);
    }
#pragma unroll
    for (int u = 0; u < 2; ++u) {
      const int sl = cur + u;
      bf16x8 a[4], b[2];
#pragma unroll
      for (int m = 0; m < 4; ++m)
        a[m] = *reinterpret_cast<const bf16x8*>(
            &As[sl][wm * 64 + m * 16 + (lane & 15)][(lane >> 4) * 8]);
#pragma unroll
      for (int n = 0; n < 2; ++n)
        b[n] = *reinterpret_cast<const bf16x8*>(
            &Bs[sl][wn * 32 + n * 16 + (lane & 15)][(lane >> 4) * 8]);
#pragma unroll
      for (int m = 0; m < 4; ++m)
#pragma unroll
        for (int n = 0; n < 2; ++n)
          acc[m][n] = __builtin_amdgcn_mfma_f32_16x16x32_bf16(a[m], b[n], acc[m][n], 0, 0, 0);
    }
    __syncthreads();
    cur = nxt;
  }
#undef STAGE

  const int row0 = tileM + wm * 64 + ((lane >> 4) << 2);
  const int col0 = tileN + wn * 32 + (lane & 15);
#pragma unroll
  for (int n = 0; n < 2; ++n) {
    const int col = col0 + n * 16;
    const float bv = (FLAGS & EP_BIAS) ? bias[col] : 0.0f;
#pragma unroll
    for (int m = 0; m < 4; ++m) {
#pragma unroll
      for (int i = 0; i < 4; ++i) {
        const int row = row0 + m * 16 + i;
        float v = acc[m][n][i];
        if (FLAGS & EP_SCALE) v *= scale;
        v += bv;
        if (FLAGS & EP_RELU) v = fmaxf(v, 0.0f);
        if (FLAGS & EP_EXP) v = __expf(v);
        if (FLAGS & EP_ROWSC) v *= rowsc[rbase + row];
        if (FLAGS & EP_RESID) v += resid[coff + (long)row * N + col];
        if (FLAGS & EP_F32) Cf[coff + (long)row * N + col] = v;
        if (FLAGS & EP_BF16) {
          if (FLAGS & EP_TRANS)
            Cb[coff + (long)col * M + row] = f2b(v);
          else
            Cb[coff + (long)row * N + col] = f2b(v);
        }
      }
    }
  }
}

// ---------- merged QKV GEMM (512 thr, 4-slot, COLUMN-CHUNKED XCD order) ----------
// r11 diagnosis: default order cycles all 24 B-panels (6 MB) through each 4 MB
// per-XCD L2 -> B never resident -> every prefetch pays L3 latency at the
// barrier drain (FETCH 77 MB vs ~22 ideal). Chunked: XCD k owns columns
// [3k, 3k+3), so its B working set is 768 KB (resident) and A panels get 3x
// immediate reuse (x-inner order).
__global__ __launch_bounds__(512) void gemm_qkv(
    const ushort* __restrict__ A, const ushort* __restrict__ Bt,
    ushort* __restrict__ Cq, ushort* __restrict__ Ck, ushort* __restrict__ Cv,
    const float* __restrict__ bq, const float* __restrict__ bk,
    const float* __restrict__ bv, int M, int N, int K) {
  const int gx = gridDim.x;               // 24
  const int cpx = gx >> 3;                // 3 columns per XCD
  const int d = blockIdx.x + gx * blockIdx.y;
  const int xcd = d & 7, j = d >> 3;
  const int tileN = (xcd * cpx + j % cpx) * 128;
  const int tileM = (j / cpx) * 128;
  const int tid = threadIdx.x, lane = tid & 63, wid = tid >> 6;
  const int wm = wid >> 2, wn = wid & 3;
  __shared__ alignas(16) ushort As[4][128][32];
  __shared__ alignas(16) ushort Bs[4][128][32];
  f32x4 acc[4][2] = {};

  const int srow = wid * 16 + (lane >> 2);
  const int scol = (lane & 3) * 8;
  const ushort* aP = A + (long)(tileM + srow) * K + scol;
  const ushort* bP = Bt + (long)(tileN + srow) * K + scol;

#define STAGE(slot, kk)                                                                  \
  do {                                                                                   \
    __builtin_amdgcn_global_load_lds(GLP(aP + (kk)), LDP(&As[slot][wid * 16][0]), 16, 0, \
                                     0);                                                 \
    __builtin_amdgcn_global_load_lds(GLP(bP + (kk)), LDP(&Bs[slot][wid * 16][0]), 16, 0, \
                                     0);                                                 \
  } while (0)

  STAGE(0, 0);
  STAGE(1, 32);
  __syncthreads();
  int cur = 0;
  for (int kk = 0; kk < K; kk += 64) {
    const int nxt = cur ^ 2;
    if (kk + 64 < K) {
      STAGE(nxt, kk + 64);
      STAGE(nxt + 1, kk + 96);
    }
#pragma unroll
    for (int u = 0; u < 2; ++u) {
      const int sl = cur + u;
      bf16x8 a[4], b[2];
#pragma unroll
      for (int m = 0; m < 4; ++m)
        a[m] = *reinterpret_cast<const bf16x8*>(
            &As[sl][wm * 64 + m * 16 + (lane & 15)][(lane >> 4) * 8]);
#pragma unroll
      for (int n = 0; n < 2; ++n)
        b[n] = *reinterpret_cast<const bf16x8*>(
            &Bs[sl][wn * 32 + n * 16 + (lane & 15)][(lane >> 4) * 8]);
#pragma unroll
      for (int m = 0; m < 4; ++m)
#pragma unroll
        for (int n = 0; n < 2; ++n)
          acc[m][n] = __builtin_amdgcn_mfma_f32_16x16x32_bf16(a[m], b[n], acc[m][n], 0, 0, 0);
    }
    __syncthreads();
    cur = nxt;
  }
#undef STAGE

  const int seg = tileN >> 10;
  const float* bias = (seg == 0) ? bq : (seg == 1) ? bk : bv;
  const int row0 = tileM + wm * 64 + ((lane >> 4) << 2);
  const int col0 = tileN + wn * 32 + (lane & 15);
#pragma unroll
  for (int n = 0; n < 2; ++n) {
    const int col = col0 + n * 16;
    const int bcol = col & 1023;
    const float bvv = bias[bcol];
#pragma unroll
    for (int m = 0; m < 4; ++m) {
#pragma unroll
      for (int i = 0; i < 4; ++i) {
        const int row = row0 + m * 16 + i;
        const float v = acc[m][n][i] + bvv;
        if (seg == 0) {
          Cq[(long)row * 1024 + bcol] = f2b(v);
        } else if (seg == 1) {
          Ck[(long)row * 1024 + bcol] = f2b(v);
        } else {
          Cv[((long)(row >> 11) * 1024 + bcol) * 2048 + (row & 2047)] = f2b(v);
        }
      }
    }
  }
}

// ---------- launch ----------
extern "C" void kernel_launch(void* const* d_in, const int* in_sizes, int n_in,
                              void* d_out, int out_size, void* d_ws, size_t ws_size,
                              hipStream_t stream) {
  const int B = 4, S = 2048, E = 1024, FFD = 1024;
  const long MS = (long)B * S;  // 8192
  const float* x   = (const float*)d_in[0];
  const float* Wq  = (const float*)d_in[1];
  const float* bq  = (const float*)d_in[2];
  const float* Wk  = (const float*)d_in[3];
  const float* bk  = (const float*)d_in[4];
  const float* Wv  = (const float*)d_in[5];
  const float* bv  = (const float*)d_in[6];
  const float* Wo  = (const float*)d_in[7];
  const float* bo  = (const float*)d_in[8];
  const float* W1  = (const float*)d_in[9];
  const float* b1  = (const float*)d_in[10];
  const float* W2  = (const float*)d_in[11];
  const float* b2  = (const float*)d_in[12];
  const float* g1  = (const float*)d_in[13];
  const float* be1 = (const float*)d_in[14];
  const float* g2  = (const float*)d_in[15];
  const float* be2 = (const float*)d_in[16];

  float* out  = (float*)d_out;           // [8192][1024]
  float* wout = out + MS * E;            // [4][2048][2048] fp32 normalized w

  ushort* xnA = (ushort*)d_ws;           // xn (LN1) then xn2 (LN2)    [8192][1024] bf16
  ushort* qB  = xnA + MS * E;            // q  then pv                 [8192][1024] bf16
  ushort* kC  = qB + MS * E;             // k  then h (ffn1)           [8192][1024] bf16
  ushort* vTD = kC + MS * E;             // vT                     [4][1024][2048] bf16
  ushort* wE  = vTD + MS * E;            // e = exp(s/32) bf16     [4][2048][2048] bf16
  float*  x2F = (float*)(wE + (long)B * S * S);  // x2 fp32         [8192][1024]
  ushort* wts = (ushort*)(x2F + MS * E);
  ushort* WqT = wts;                     // [3072][1024] concatenated WqT|WkT|WvT
  ushort* WkT = WqT + (long)E * E;
  ushort* WvT = WkT + (long)E * E;
  ushort* WoT = WvT + (long)E * E;
  ushort* W1T = WoT + (long)E * E;
  ushort* W2T = W1T + (long)E * FFD;
  float*  invZ = (float*)(W2T + (long)FFD * E);  // [8192] fp32

  hipLaunchKernelGGL(wtrans6_kernel, dim3(E / 32, E / 32, 6), dim3(32, 8), 0, stream,
                     Wq, Wk, Wv, Wo, W1, W2, WqT, WkT, WvT, WoT, W1T, W2T);

  // LN1: x -> xn (bf16)
  hipLaunchKernelGGL(layernorm_kernel, dim3(MS), dim3(256), 0, stream, x, g1, be1, xnA);

  // merged QKV: [8192,1024] @ [3072,1024]^T -> q, k, vT  (column-chunked XCD)
  hipLaunchKernelGGL(gemm_qkv, dim3(3 * E / 128, MS / 128, 1), dim3(512), 0, stream,
                     xnA, WqT, qB, kC, vTD, bq, bk, bv, (int)MS, 3 * E, E);

  // e = exp(q_b @ k_b^T / 32) -> bf16 wE  (swizzled square grid)
  hipLaunchKernelGGL((gemm_bt<EP_BF16 | EP_SCALE | EP_EXP | EP_SWZ>),
                     dim3(S / 128, S / 128, B), dim3(512), 0, stream,
                     qB, kC, (float*)nullptr, wE, (const float*)nullptr,
                     (const float*)nullptr, (const float*)nullptr,
                     S, S, E, 0.03125f, (long)S * E, (long)S * E, (long)S * S);

  // normalize: w fp32 -> d_out, invZ for PV
  hipLaunchKernelGGL(rownorm_kernel, dim3(B * S), dim3(256), 0, stream, wE, wout, invZ);

  // pv = (e_b @ v_b) * invZ[row]  -> bf16 [8192][1024]
  hipLaunchKernelGGL((gemm_bt<EP_BF16 | EP_ROWSC | EP_SWZ>), dim3(E / 128, S / 128, B),
                     dim3(512), 0, stream, wE, vTD, (float*)nullptr, qB,
                     (const float*)nullptr, (const float*)nullptr, invZ,
                     S, E, S, 1.0f, (long)S * S, (long)E * S, (long)S * E);

  // x2 = x + pv @ Wo + bo  (fp32)
  hipLaunchKernelGGL((gemm_bt<EP_F32 | EP_BIAS | EP_RESID | EP_SWZ>),
                     dim3(E / 128, MS / 128, 1), dim3(512), 0, stream, qB, WoT, x2F,
                     (ushort*)nullptr, bo, x, (const float*)nullptr,
                     (int)MS, E, E, 1.0f, 0L, 0L, 0L);

  // LN2: x2 -> xn2 (bf16)
  hipLaunchKernelGGL(layernorm_kernel, dim3(MS), dim3(256), 0, stream, x2F, g2, be2, xnA);

  // h = relu(xn2 @ W1 + b1)  (bf16)
  hipLaunchKernelGGL((gemm_bt<EP_BF16 | EP_BIAS | EP_RELU | EP_SWZ>),
                     dim3(FFD / 128, MS / 128, 1), dim3(512), 0, stream, xnA, W1T,
                     (float*)nullptr, kC, b1, (const float*)nullptr, (const float*)nullptr,
                     (int)MS, FFD, E, 1.0f, 0L, 0L, 0L);

  // out = x2 + h @ W2 + b2  (fp32 -> d_out)
  hipLaunchKernelGGL((gemm_bt<EP_F32 | EP_BIAS | EP_RESID | EP_SWZ>),
                     dim3(E / 128, MS / 128, 1), dim3(512), 0, stream, kC, W2T, out,
                     (ushort*)nullptr, b2, x2F, (const float*)nullptr,
                     (int)MS, E, FFD, 1.0f, 0L, 0L, 0L);
}

// Round 13
// 316.022 us; speedup vs baseline: 1.0261x; 1.0261x over previous
//
#include <hip/hip_runtime.h>

// ---------- types & helpers ----------
typedef __attribute__((ext_vector_type(8))) __bf16 bf16x8;
typedef __attribute__((ext_vector_type(4))) float f32x4;
typedef __attribute__((ext_vector_type(8))) ushort ushort8;

#define GLP(p) ((const __attribute__((address_space(1))) void*)(p))
#define LDP(p) ((__attribute__((address_space(3))) void*)(p))

__device__ __forceinline__ ushort f2b(float f) {
  union { float f; uint u; } c; c.f = f;
  uint u = c.u;
  uint r = (u + 0x7fffu + ((u >> 16) & 1u)) >> 16;
  return (ushort)r;
}
__device__ __forceinline__ float b2f(ushort b) {
  union { uint u; float f; } c; c.u = ((uint)b) << 16;
  return c.f;
}

// bijective XCD swizzle, row-chunks (good for square attention grids; r10).
__device__ __forceinline__ void xcd_tiles(int& tileN, int& tileM) {
  const int gx = gridDim.x;
  const int nwg = gx * gridDim.y;
  int id = blockIdx.x + gx * blockIdx.y;
  id = (id & 7) * (nwg >> 3) + (id >> 3);
  tileN = (id % gx) * 128;
  tileM = (id / gx) * 128;
}

__device__ __forceinline__ float block_reduce_sum(float v, float* sm) {
#pragma unroll
  for (int off = 1; off < 64; off <<= 1) v += __shfl_xor(v, off);
  const int wave = threadIdx.x >> 6, lane = threadIdx.x & 63;
  __syncthreads();
  if (lane == 0) sm[wave] = v;
  __syncthreads();
  return sm[0] + sm[1] + sm[2] + sm[3];
}

// ---------- fused weight transpose + bf16 convert for all 6 weights ----------
__global__ __launch_bounds__(256) void wtrans6_kernel(
    const float* __restrict__ W0, const float* __restrict__ W1,
    const float* __restrict__ W2, const float* __restrict__ W3,
    const float* __restrict__ W4, const float* __restrict__ W5,
    ushort* __restrict__ T0, ushort* __restrict__ T1, ushort* __restrict__ T2,
    ushort* __restrict__ T3, ushort* __restrict__ T4, ushort* __restrict__ T5) {
  __shared__ float tile[32][33];
  const float* Ws[6] = {W0, W1, W2, W3, W4, W5};
  ushort* Ts[6] = {T0, T1, T2, T3, T4, T5};
  const float* W = Ws[blockIdx.z];
  ushort* Wt = Ts[blockIdx.z];
  const int K = 1024, N = 1024;
  const int n0 = blockIdx.x * 32, k0 = blockIdx.y * 32;
  const int tx = threadIdx.x, ty = threadIdx.y;  // block (32,8)
#pragma unroll
  for (int i = 0; i < 32; i += 8)
    tile[ty + i][tx] = W[(long)(k0 + ty + i) * N + n0 + tx];
  __syncthreads();
#pragma unroll
  for (int i = 0; i < 32; i += 8)
    Wt[(long)(n0 + ty + i) * K + k0 + tx] = f2b(tile[tx][ty + i]);
}

// ---------- LayerNorm (row of 1024) -> bf16 ----------
__global__ __launch_bounds__(256) void layernorm_kernel(
    const float* __restrict__ x, const float* __restrict__ g,
    const float* __restrict__ be, ushort* __restrict__ out) {
  __shared__ float sm[4];
  const long row = blockIdx.x;
  const float4 v = reinterpret_cast<const float4*>(x + row * 1024)[threadIdx.x];
  float s = v.x + v.y + v.z + v.w;
  s = block_reduce_sum(s, sm);
  const float mu = s * (1.0f / 1024.0f);
  const float dx = v.x - mu, dy = v.y - mu, dz = v.z - mu, dw = v.w - mu;
  float s2 = dx * dx + dy * dy + dz * dz + dw * dw;
  s2 = block_reduce_sum(s2, sm);
  const float rstd = rsqrtf(s2 * (1.0f / 1024.0f) + 1e-5f);
  const float4 gg = reinterpret_cast<const float4*>(g)[threadIdx.x];
  const float4 bb = reinterpret_cast<const float4*>(be)[threadIdx.x];
  ushort4 o;
  o.x = f2b(dx * rstd * gg.x + bb.x);
  o.y = f2b(dy * rstd * gg.y + bb.y);
  o.z = f2b(dz * rstd * gg.z + bb.z);
  o.w = f2b(dw * rstd * gg.w + bb.w);
  reinterpret_cast<ushort4*>(out + row * 1024)[threadIdx.x] = o;
}

// ---------- row-normalize: e(bf16) -> w(fp32, normalized) + invZ ----------
__global__ __launch_bounds__(256) void rownorm_kernel(
    const ushort* __restrict__ e, float* __restrict__ w, float* __restrict__ invZ) {
  __shared__ float sm[4];
  const long row = blockIdx.x;
  const ushort8 v = *reinterpret_cast<const ushort8*>(e + row * 2048 + threadIdx.x * 8);
  float f[8];
  float s = 0.0f;
#pragma unroll
  for (int i = 0; i < 8; ++i) {
    f[i] = b2f(v[i]);
    s += f[i];
  }
  s = block_reduce_sum(s, sm);
  const float inv = 1.0f / s;
  if (threadIdx.x == 0) invZ[row] = inv;
  float4 o0 = {f[0] * inv, f[1] * inv, f[2] * inv, f[3] * inv};
  float4 o1 = {f[4] * inv, f[5] * inv, f[6] * inv, f[7] * inv};
  float4* wp = reinterpret_cast<float4*>(w + row * 2048);
  wp[threadIdx.x * 2] = o0;
  wp[threadIdx.x * 2 + 1] = o1;
}

// ---------- 128x128 GEMM, 8 waves, 4-slot 2-step-unrolled prefetch ----------
#define EP_BF16 1
#define EP_F32 2
#define EP_BIAS 4
#define EP_RELU 8
#define EP_SCALE 16
#define EP_RESID 32
#define EP_TRANS 64
#define EP_EXP 128     // v = exp(v) after scale (QK^T -> e)
#define EP_ROWSC 256   // v *= rowsc[z*M + row]  (PV normalization)
#define EP_SWZ 512     // apply XCD tile swizzle

template <int FLAGS>
__global__ __launch_bounds__(512) void gemm_bt(
    const ushort* __restrict__ A, const ushort* __restrict__ Bt,
    float* __restrict__ Cf, ushort* __restrict__ Cb,
    const float* __restrict__ bias, const float* __restrict__ resid,
    const float* __restrict__ rowsc,
    int M, int N, int K, float scale, long sA, long sB, long sC) {
  A += (long)blockIdx.z * sA;
  Bt += (long)blockIdx.z * sB;
  const long coff = (long)blockIdx.z * sC;
  const long rbase = (long)blockIdx.z * M;
  int tileN, tileM;
  if (FLAGS & EP_SWZ) {
    xcd_tiles(tileN, tileM);
  } else {
    tileN = blockIdx.x * 128;
    tileM = blockIdx.y * 128;
  }
  const int tid = threadIdx.x, lane = tid & 63, wid = tid >> 6;  // 8 waves
  const int wm = wid >> 2, wn = wid & 3;
  __shared__ alignas(16) ushort As[4][128][32];
  __shared__ alignas(16) ushort Bs[4][128][32];
  f32x4 acc[4][2] = {};

  const int srow = wid * 16 + (lane >> 2);
  const int scol = (lane & 3) * 8;
  const ushort* aP = A + (long)(tileM + srow) * K + scol;
  const ushort* bP = Bt + (long)(tileN + srow) * K + scol;

#define STAGE(slot, kk)                                                                  \
  do {                                                                                   \
    __builtin_amdgcn_global_load_lds(GLP(aP + (kk)), LDP(&As[slot][wid * 16][0]), 16, 0, \
                                     0);                                                 \
    __builtin_amdgcn_global_load_lds(GLP(bP + (kk)), LDP(&Bs[slot][wid * 16][0]), 16, 0, \
                                     0);                                                 \
  } while (0)

  STAGE(0, 0);
  STAGE(1, 32);
  __syncthreads();
  int cur = 0;
  for (int kk = 0; kk < K; kk += 64) {
    const int nxt = cur ^ 2;
    if (kk + 64 < K) {
      STAGE(nxt, kk + 64);
      STAGE(nxt + 1, kk + 96);
    }
#pragma unroll
    for (int u = 0; u < 2; ++u) {
      const int sl = cur + u;
      bf16x8 a[4], b[2];
#pragma unroll
      for (int m = 0; m < 4; ++m)
        a[m] = *reinterpret_cast<const bf16x8*>(
            &As[sl][wm * 64 + m * 16 + (lane & 15)][(lane >> 4) * 8]);
#pragma unroll
      for (int n = 0; n < 2; ++n)
        b[n] = *reinterpret_cast<const bf16x8*>(
            &Bs[sl][wn * 32 + n * 16 + (lane & 15)][(lane >> 4) * 8]);
#pragma unroll
      for (int m = 0; m < 4; ++m)
#pragma unroll
        for (int n = 0; n < 2; ++n)
          acc[m][n] = __builtin_amdgcn_mfma_f32_16x16x32_bf16(a[m], b[n], acc[m][n], 0, 0, 0);
    }
    __syncthreads();
    cur = nxt;
  }
#undef STAGE

  const int row0 = tileM + wm * 64 + ((lane >> 4) << 2);
  const int col0 = tileN + wn * 32 + (lane & 15);
#pragma unroll
  for (int n = 0; n < 2; ++n) {
    const int col = col0 + n * 16;
    const float bv = (FLAGS & EP_BIAS) ? bias[col] : 0.0f;
#pragma unroll
    for (int m = 0; m < 4; ++m) {
#pragma unroll
      for (int i = 0; i < 4; ++i) {
        const int row = row0 + m * 16 + i;
        float v = acc[m][n][i];
        if (FLAGS & EP_SCALE) v *= scale;
        v += bv;
        if (FLAGS & EP_RELU) v = fmaxf(v, 0.0f);
        if (FLAGS & EP_EXP) v = __expf(v);
        if (FLAGS & EP_ROWSC) v *= rowsc[rbase + row];
        if (FLAGS & EP_RESID) v += resid[coff + (long)row * N + col];
        if (FLAGS & EP_F32) Cf[coff + (long)row * N + col] = v;
        if (FLAGS & EP_BF16) {
          if (FLAGS & EP_TRANS)
            Cb[coff + (long)col * M + row] = f2b(v);
          else
            Cb[coff + (long)row * N + col] = f2b(v);
        }
      }
    }
  }
}

// ---------- merged QKV GEMM: r9-era 2-slot schedule (32 KiB LDS) ----------
// QKV is L2-miss-latency-bound and wants OCCUPANCY (r9: 2-slot, 52% occ,
// 104.6 us) -- the 4-slot unroll halves blocks/CU and hurts it (r10/r12:
// 33% occ, 108-114 us). Linear tile order (both swizzles measured worse).
__global__ __launch_bounds__(512) void gemm_qkv(
    const ushort* __restrict__ A, const ushort* __restrict__ Bt,
    ushort* __restrict__ Cq, ushort* __restrict__ Ck, ushort* __restrict__ Cv,
    const float* __restrict__ bq, const float* __restrict__ bk,
    const float* __restrict__ bv, int M, int N, int K) {
  const int tileN = blockIdx.x * 128, tileM = blockIdx.y * 128;
  const int tid = threadIdx.x, lane = tid & 63, wid = tid >> 6;
  const int wm = wid >> 2, wn = wid & 3;
  __shared__ alignas(16) ushort As[2][128][32];
  __shared__ alignas(16) ushort Bs[2][128][32];
  f32x4 acc[4][2] = {};

  const int srow = wid * 16 + (lane >> 2);
  const int scol = (lane & 3) * 8;
  const ushort* aP = A + (long)(tileM + srow) * K + scol;
  const ushort* bP = Bt + (long)(tileN + srow) * K + scol;

#define STAGE(buf, kk)                                                                   \
  do {                                                                                   \
    __builtin_amdgcn_global_load_lds(GLP(aP + (kk)), LDP(&As[buf][wid * 16][0]), 16, 0,  \
                                     0);                                                 \
    __builtin_amdgcn_global_load_lds(GLP(bP + (kk)), LDP(&Bs[buf][wid * 16][0]), 16, 0,  \
                                     0);                                                 \
  } while (0)

  STAGE(0, 0);
  __syncthreads();
  int cur = 0;
  for (int kk = 0; kk < K; kk += 32) {
    const int nxt = cur ^ 1;
    if (kk + 32 < K) STAGE(nxt, kk + 32);
    bf16x8 a[4], b[2];
#pragma unroll
    for (int m = 0; m < 4; ++m)
      a[m] = *reinterpret_cast<const bf16x8*>(
          &As[cur][wm * 64 + m * 16 + (lane & 15)][(lane >> 4) * 8]);
#pragma unroll
    for (int n = 0; n < 2; ++n)
      b[n] = *reinterpret_cast<const bf16x8*>(
          &Bs[cur][wn * 32 + n * 16 + (lane & 15)][(lane >> 4) * 8]);
#pragma unroll
    for (int m = 0; m < 4; ++m)
#pragma unroll
      for (int n = 0; n < 2; ++n)
        acc[m][n] = __builtin_amdgcn_mfma_f32_16x16x32_bf16(a[m], b[n], acc[m][n], 0, 0, 0);
    __syncthreads();
    cur = nxt;
  }
#undef STAGE

  const int seg = tileN >> 10;
  const float* bias = (seg == 0) ? bq : (seg == 1) ? bk : bv;
  const int row0 = tileM + wm * 64 + ((lane >> 4) << 2);
  const int col0 = tileN + wn * 32 + (lane & 15);
#pragma unroll
  for (int n = 0; n < 2; ++n) {
    const int col = col0 + n * 16;
    const int bcol = col & 1023;
    const float bvv = bias[bcol];
#pragma unroll
    for (int m = 0; m < 4; ++m) {
#pragma unroll
      for (int i = 0; i < 4; ++i) {
        const int row = row0 + m * 16 + i;
        const float v = acc[m][n][i] + bvv;
        if (seg == 0) {
          Cq[(long)row * 1024 + bcol] = f2b(v);
        } else if (seg == 1) {
          Ck[(long)row * 1024 + bcol] = f2b(v);
        } else {
          Cv[((long)(row >> 11) * 1024 + bcol) * 2048 + (row & 2047)] = f2b(v);
        }
      }
    }
  }
}

// ---------- launch ----------
extern "C" void kernel_launch(void* const* d_in, const int* in_sizes, int n_in,
                              void* d_out, int out_size, void* d_ws, size_t ws_size,
                              hipStream_t stream) {
  const int B = 4, S = 2048, E = 1024, FFD = 1024;
  const long MS = (long)B * S;  // 8192
  const float* x   = (const float*)d_in[0];
  const float* Wq  = (const float*)d_in[1];
  const float* bq  = (const float*)d_in[2];
  const float* Wk  = (const float*)d_in[3];
  const float* bk  = (const float*)d_in[4];
  const float* Wv  = (const float*)d_in[5];
  const float* bv  = (const float*)d_in[6];
  const float* Wo  = (const float*)d_in[7];
  const float* bo  = (const float*)d_in[8];
  const float* W1  = (const float*)d_in[9];
  const float* b1  = (const float*)d_in[10];
  const float* W2  = (const float*)d_in[11];
  const float* b2  = (const float*)d_in[12];
  const float* g1  = (const float*)d_in[13];
  const float* be1 = (const float*)d_in[14];
  const float* g2  = (const float*)d_in[15];
  const float* be2 = (const float*)d_in[16];

  float* out  = (float*)d_out;           // [8192][1024]
  float* wout = out + MS * E;            // [4][2048][2048] fp32 normalized w

  ushort* xnA = (ushort*)d_ws;           // xn (LN1) then xn2 (LN2)    [8192][1024] bf16
  ushort* qB  = xnA + MS * E;            // q  then pv                 [8192][1024] bf16
  ushort* kC  = qB + MS * E;             // k  then h (ffn1)           [8192][1024] bf16
  ushort* vTD = kC + MS * E;             // vT                     [4][1024][2048] bf16
  ushort* wE  = vTD + MS * E;            // e = exp(s/32) bf16     [4][2048][2048] bf16
  float*  x2F = (float*)(wE + (long)B * S * S);  // x2 fp32         [8192][1024]
  ushort* wts = (ushort*)(x2F + MS * E);
  ushort* WqT = wts;                     // [3072][1024] concatenated WqT|WkT|WvT
  ushort* WkT = WqT + (long)E * E;
  ushort* WvT = WkT + (long)E * E;
  ushort* WoT = WvT + (long)E * E;
  ushort* W1T = WoT + (long)E * E;
  ushort* W2T = W1T + (long)E * FFD;
  float*  invZ = (float*)(W2T + (long)FFD * E);  // [8192] fp32

  hipLaunchKernelGGL(wtrans6_kernel, dim3(E / 32, E / 32, 6), dim3(32, 8), 0, stream,
                     Wq, Wk, Wv, Wo, W1, W2, WqT, WkT, WvT, WoT, W1T, W2T);

  // LN1: x -> xn (bf16)
  hipLaunchKernelGGL(layernorm_kernel, dim3(MS), dim3(256), 0, stream, x, g1, be1, xnA);

  // merged QKV: [8192,1024] @ [3072,1024]^T -> q, k, vT  (2-slot, linear order)
  hipLaunchKernelGGL(gemm_qkv, dim3(3 * E / 128, MS / 128, 1), dim3(512), 0, stream,
                     xnA, WqT, qB, kC, vTD, bq, bk, bv, (int)MS, 3 * E, E);

  // e = exp(q_b @ k_b^T / 32) -> bf16 wE  (swizzled square grid)
  hipLaunchKernelGGL((gemm_bt<EP_BF16 | EP_SCALE | EP_EXP | EP_SWZ>),
                     dim3(S / 128, S / 128, B), dim3(512), 0, stream,
                     qB, kC, (float*)nullptr, wE, (const float*)nullptr,
                     (const float*)nullptr, (const float*)nullptr,
                     S, S, E, 0.03125f, (long)S * E, (long)S * E, (long)S * S);

  // normalize: w fp32 -> d_out, invZ for PV
  hipLaunchKernelGGL(rownorm_kernel, dim3(B * S), dim3(256), 0, stream, wE, wout, invZ);

  // pv = (e_b @ v_b) * invZ[row]  -> bf16 [8192][1024]
  hipLaunchKernelGGL((gemm_bt<EP_BF16 | EP_ROWSC | EP_SWZ>), dim3(E / 128, S / 128, B),
                     dim3(512), 0, stream, wE, vTD, (float*)nullptr, qB,
                     (const float*)nullptr, (const float*)nullptr, invZ,
                     S, E, S, 1.0f, (long)S * S, (long)E * S, (long)S * E);

  // x2 = x + pv @ Wo + bo  (fp32)
  hipLaunchKernelGGL((gemm_bt<EP_F32 | EP_BIAS | EP_RESID | EP_SWZ>),
                     dim3(E / 128, MS / 128, 1), dim3(512), 0, stream, qB, WoT, x2F,
                     (ushort*)nullptr, bo, x, (const float*)nullptr,
                     (int)MS, E, E, 1.0f, 0L, 0L, 0L);

  // LN2: x2 -> xn2 (bf16)
  hipLaunchKernelGGL(layernorm_kernel, dim3(MS), dim3(256), 0, stream, x2F, g2, be2, xnA);

  // h = relu(xn2 @ W1 + b1)  (bf16)
  hipLaunchKernelGGL((gemm_bt<EP_BF16 | EP_BIAS | EP_RELU | EP_SWZ>),
                     dim3(FFD / 128, MS / 128, 1), dim3(512), 0, stream, xnA, W1T,
                     (float*)nullptr, kC, b1, (const float*)nullptr, (const float*)nullptr,
                     (int)MS, FFD, E, 1.0f, 0L, 0L, 0L);

  // out = x2 + h @ W2 + b2  (fp32 -> d_out)
  hipLaunchKernelGGL((gemm_bt<EP_F32 | EP_BIAS | EP_RESID | EP_SWZ>),
                     dim3(E / 128, MS / 128, 1), dim3(512), 0, stream, kC, W2T, out,
                     (ushort*)nullptr, b2, x2F, (const float*)nullptr,
                     (int)MS, E, FFD, 1.0f, 0L, 0L, 0L);
}